// Round 1
// baseline (1606.830 us; speedup 1.0000x reference)
//
#include <hip/hip_runtime.h>
#include <cstdint>
#include <cstddef>

// Problem constants
#define Hh 2048
#define Vv 32000
#define Bb 16
#define Ss 256

typedef unsigned short ushort_t;
typedef unsigned int   uint_t;
typedef unsigned long long ull_t;

typedef __attribute__((ext_vector_type(8))) short short8;   // 8 x bf16 (4 VGPRs)
typedef __attribute__((ext_vector_type(4))) float f32x4;    // MFMA accumulator

// ---- workspace layout (bytes) ----
// Zbuf : 3 physical slots x [b16][h2048] bf16 z~ = exp(y - mhat), epoch parity
//        encoded in the SIGN BITS (values are >= 0, sign bit is free).
// Y255 : [b][h] f32 final-step y
#define Z_OFF    0ull
#define Z_SLOT   ((size_t)Bb * Hh * 2)          // 64 KiB per slot
#define Z_BYTES  ((size_t)3 * Z_SLOT)
#define Y_OFF    (Z_OFF + Z_BYTES)
#define Y_BYTES  ((size_t)Bb * Hh * 4)
#define WS_NEED  (Y_OFF + Y_BYTES)

// Relaxed agent-scope atomics. Protocol: the DATA is the flag.
//  - step k publishes z~^k to physical slot phys(k%3) with all 16 bf16 sign
//    bits = k&1 (fire-and-forget 8B atomic stores, no drain, no counter).
//  - step k consumer spins on its own 8B granules of slot phys((k-1)%3)
//    until every sign bit == (k-1)&1. Discovery and data fetch are the same
//    load. Stale data in a slot is exactly 3 steps old -> opposite parity.
//    >=6-step skew is impossible: every WG consumes every WG's chunk each
//    step, so no producer can run 2 full steps ahead of any consumer.
//  - phys(b) = (3-b)%3 so the per-launch init patterns are contiguous:
//    [phys0,phys1]=0x80 (sign=1), [phys2]=0x00 (sign=0) -> two memsets, and
//    each slot's first poll sees the WRONG parity until real data lands
//    (also scrubs the previous launch's leftovers).
// Global max exchange is GONE: z~ is scaled by a lagged max mhat that every
// WG derives bit-identically from the staged data itself:
//    mhat_k = mhat_{k-1} + log(max_h z~^{k-1}[h])   (mhat_0 = 0)
// Rows of alpha sum to 1 and ip<=0  =>  y^k <= max y^{k-1}  =>  z~ <= ~1.
#define LD_REL(p)     __hip_atomic_load((p), __ATOMIC_RELAXED, __HIP_MEMORY_SCOPE_AGENT)
#define ST_REL(p, v)  __hip_atomic_store((p), (v), __ATOMIC_RELAXED, __HIP_MEMORY_SCOPE_AGENT)

#define SGN64 0x8000800080008000ull
#define MAG64 0x7FFF7FFF7FFF7FFFull

__device__ __forceinline__ float b2f_u(uint_t u) {
  union { uint_t u; float f; } x; x.u = u; return x.f;
}
__device__ __forceinline__ ushort_t f2b(float f) {
  union { float f; uint_t u; } x; x.f = f;
  uint_t u = x.u;
  return (ushort_t)((u + 0x7FFFu + ((u >> 16) & 1u)) >> 16);   // RNE f32->bf16
}
__device__ __forceinline__ uint_t umaxu(uint_t a, uint_t b) { return a > b ? a : b; }
// packed 2 x u16 max (positive bf16 ordering == integer ordering)
__device__ __forceinline__ uint_t pkmax16(uint_t a, uint_t b) {
  uint_t lo = umaxu(a & 0xFFFFu, b & 0xFFFFu);
  uint_t hi = umaxu(a >> 16, b >> 16);
  return lo | (hi << 16);
}

// ---------------------------------------------------------------------------
// Persistent scan kernel. 256 WGs x 256 threads.
// 8 independent column-groups (g = blockIdx & 7) of 32 WGs; group g owns
// batch columns {2g, 2g+1}. WG wl owns rows [wl*64, wl*64+64); each of its
// 4 waves holds 16 alpha rows as register-resident bf16 A-fragments.
// ---------------------------------------------------------------------------
__global__ __launch_bounds__(256, 1) void hmm_persist(
    const float* __restrict__ alpha,
    const float* __restrict__ beta,
    const int*  __restrict__ ids,
    ushort_t* __restrict__ Zbuf,
    float* __restrict__ Y255,
    float* __restrict__ out)
{
  const int w    = blockIdx.x;
  const int g    = w & 7;
  const int wl   = w >> 3;         // 0..31 within group -> row chunk
  const int c0   = g * 2;          // first batch column of group
  const int tid  = threadIdx.x;
  const int wv   = tid >> 6;       // wave 0..3
  const int lane = tid & 63;
  const int lrow = lane & 15;
  const int quad = lane >> 4;
  const int r0   = wl * 64 + wv * 16;

  __shared__ __align__(16) ushort_t zTf[2 * 2080];  // 2 cols x (2048+32 pad)
  __shared__ float ybuf[128];      // init only
  __shared__ float ipld[128];      // ip_rev[k] for this WG: [rr][c]
  __shared__ uint_t redm[4];       // per-wave packed (c0max | c1max<<16)

  ull_t*  Zb64 = (ull_t*)Zbuf;
  uint_t* Zb32 = (uint_t*)Zbuf;

  // ---- preload alpha A-fragments (rows r0..r0+15, K=2048), f32 -> bf16 ----
  short8 afr[64];
  {
    const float* arow = alpha + (size_t)(r0 + lrow) * Hh + quad * 8;
    #pragma unroll
    for (int kt = 0; kt < 64; ++kt) {
      float4 f0 = *(const float4*)(arow + kt * 32);
      float4 f1 = *(const float4*)(arow + kt * 32 + 4);
      short8 fr;
      fr[0] = (short)f2b(f0.x); fr[1] = (short)f2b(f0.y);
      fr[2] = (short)f2b(f0.z); fr[3] = (short)f2b(f0.w);
      fr[4] = (short)f2b(f1.x); fr[5] = (short)f2b(f1.y);
      fr[6] = (short)f2b(f1.z); fr[7] = (short)f2b(f1.w);
      afr[kt] = fr;
    }
  }

  const int myc = tid & 1;                 // gather mapping for tid<128
  const int myr = wl * 64 + (tid >> 1);
  float ipreg = 0.f;

  // ---- init (k=0): y^(0)=ip_rev[0]; publish z~^(0)=exp(y^0) (mhat_0 = 0),
  //      parity 0, physical slot 0 ----
  {
    float yv = 0.f;
    if (tid < 128) {
      const int v = ids[(c0 + myc) * Ss + (Ss - 1)];
      yv = beta[(size_t)myr * Vv + v];
      ybuf[tid] = yv;
      out[(size_t)myr * Bb + (c0 + myc)] = yv;   // ys[0][h][b]
    }
    __syncthreads();
    if (tid < 64) {
      const int c = tid >> 5, rr0 = (tid & 31) * 2;
      uint_t lo = f2b(__expf(ybuf[rr0 * 2 + c]));
      uint_t hi = f2b(__expf(ybuf[rr0 * 2 + 2 + c]));
      ST_REL(Zb32 + (size_t)(c0 + c) * 1024 + (wl * 32 + (tid & 31)),
             lo | (hi << 16));                   // sign bits 0 == parity(0)
    }
    if (tid < 128) {   // prefetch ip_rev[1]
      const int v1 = ids[(c0 + myc) * Ss + (Ss - 2)];
      ipreg = beta[(size_t)myr * Vv + v1];
    }
  }

  float mprev = 0.f;                        // mhat_{k-1} for my column (lrow&1)
  const ushort_t* zbase = zTf + (lrow & 1) * 2080 + quad * 8;

  for (int k = 1; k < Ss; ++k) {
    const int   physR = (3 - ((k - 1) % 3)) % 3;
    const ull_t expS  = ((k - 1) & 1) ? SGN64 : 0ull;

    // ---- poll-is-the-load: spin on my 4 granules until parity matches ----
    ull_t zr[4];
    ull_t* zp[4];
    #pragma unroll
    for (int j = 0; j < 4; ++j) {
      const int idx = j * 256 + tid;        // 0..1023 ull over 2 cols
      const int c   = idx >> 9;
      const int h4  = idx & 511;
      zp[j] = Zb64 + (size_t)physR * (Bb * 512) + (size_t)(c0 + c) * 512 + h4;
      zr[j] = LD_REL(zp[j]);
    }
    while (true) {
      int bad = 0;
      #pragma unroll
      for (int j = 0; j < 4; ++j)
        if ((zr[j] & SGN64) != expS) bad |= (1 << j);
      if (!bad) break;
      #pragma unroll
      for (int j = 0; j < 4; ++j)
        if (bad & (1 << j)) zr[j] = LD_REL(zp[j]);
    }

    // ---- stage raw z~ into LDS (strip parity signs) + per-thread col max ----
    uint_t mloc[2] = {0u, 0u};
    #pragma unroll
    for (int j = 0; j < 4; ++j) {
      const ull_t v = zr[j] & MAG64;
      const int idx = j * 256 + tid;
      const int c   = idx >> 9;              // j<2 -> col0, j>=2 -> col1
      const int h   = (idx & 511) * 4;
      *(ull_t*)(zTf + c * 2080 + h) = v;
      uint_t a = (uint_t)v, b = (uint_t)(v >> 32);
      uint_t m2 = pkmax16(a, b);
      mloc[j >> 1] = umaxu(mloc[j >> 1], umaxu(m2 & 0xFFFFu, m2 >> 16));
    }
    if (tid < 128) ipld[tid] = ipreg;

    // wave-level packed max reduce, then cross-wave via LDS at the barrier
    uint_t pk = mloc[0] | (mloc[1] << 16);
    #pragma unroll
    for (int d = 1; d < 64; d <<= 1)
      pk = pkmax16(pk, __shfl_xor(pk, d));
    if (lane == 0) redm[wv] = pk;
    __syncthreads();                                   // S4

    const uint_t rr  = pkmax16(pkmax16(redm[0], redm[1]),
                               pkmax16(redm[2], redm[3]));
    const uint_t mzb = (((lrow & 1) ? (rr >> 16) : (rr & 0xFFFFu)) << 16);
    const float  lmax = __logf(b2f_u(mzb));  // mhat_k = mprev + lmax (bit-
                                             // identical across all 32 WGs)

    // ---- prefetch ip_rev[k+1] (overlapped with MFMA) ----
    if (k < Ss - 1 && tid < 128) {
      const int v = ids[(c0 + myc) * Ss + (Ss - 2 - k)];
      ipreg = beta[(size_t)myr * Vv + v];
    }

    // ---- MFMA K-loop: D = alpha_rows @ z~  (8 independent acc chains) ----
    f32x4 acc[8];
    {
      f32x4 zv = {0.f, 0.f, 0.f, 0.f};
      #pragma unroll
      for (int j = 0; j < 8; ++j) acc[j] = zv;
    }
    #pragma unroll
    for (int kt = 0; kt < 64; ++kt) {
      short8 bfr = *(const short8*)(zbase + kt * 32);
      acc[kt & 7] = __builtin_amdgcn_mfma_f32_16x16x32_bf16(afr[kt], bfr, acc[kt & 7], 0, 0, 0);
    }
    f32x4 sf = ((acc[0] + acc[1]) + (acc[2] + acc[3])) +
               ((acc[4] + acc[5]) + (acc[6] + acc[7]));

    // ---- epilogue: y = log(D) + mhat_{k-1} + ip; publish z~^k immediately ----
    const int  c   = lrow;                 // D col = batch col (aliased &1)
    const int  rb  = r0 + quad * 4;        // D rows = quad*4 + reg
    const int  lrr = wv * 16 + quad * 4;   // row within WG chunk
    const bool act = (lrow < 2);
    const int   physW = (3 - (k % 3)) % 3;
    const ull_t orS   = (k & 1) ? SGN64 : 0ull;
    const float mnew  = mprev + lmax;      // mhat_k
    if (act) {
      float yv4[4];
      #pragma unroll
      for (int i = 0; i < 4; ++i)
        yv4[i] = __logf(sf[i]) + mprev + ipld[(lrr + i) * 2 + c];
      uint_t o0 = (uint_t)f2b(__expf(yv4[0] - mnew)) |
                  ((uint_t)f2b(__expf(yv4[1] - mnew)) << 16);
      uint_t o1 = (uint_t)f2b(__expf(yv4[2] - mnew)) |
                  ((uint_t)f2b(__expf(yv4[3] - mnew)) << 16);
      // fire-and-forget publish: data carries the epoch in its sign bits
      ST_REL(Zb64 + (size_t)physW * (Bb * 512) + (size_t)(c0 + c) * 512 + (rb >> 2),
             ((ull_t)o0 | ((ull_t)o1 << 32)) | orS);
      // off critical path: ys[k] (nobody reads `out` intra-kernel)
      #pragma unroll
      for (int i = 0; i < 4; ++i)
        out[(size_t)k * (Hh * Bb) + (size_t)(rb + i) * Bb + (c0 + c)] = yv4[i];
      if (k == Ss - 1) {
        float4 yo; yo.x = yv4[0]; yo.y = yv4[1]; yo.z = yv4[2]; yo.w = yv4[3];
        *(float4*)(Y255 + (size_t)(c0 + c) * Hh + rb) = yo;
      }
    }
    mprev = mnew;
    __syncthreads();   // protect zTf/ipld/redm against next iteration's writes
  }
}

// ---------------------------------------------------------------------------
// final[b] = log(sum_h e^{(g[h]-gm)+(y[h]-ym)}) - log(sum_h e^{g[h]-gm}) + ym
// ---------------------------------------------------------------------------
__global__ __launch_bounds__(256) void final_k(
    const float* __restrict__ gamma, const float* __restrict__ Y255,
    float* __restrict__ out)
{
  const int b = blockIdx.x;
  const int tid = threadIdx.x;
  __shared__ float sb[256];

  float ym = -3.0e38f;
  for (int h = tid; h < Hh; h += 256) ym = fmaxf(ym, Y255[(size_t)b * Hh + h]);
  sb[tid] = ym; __syncthreads();
  for (int off = 128; off; off >>= 1) {
    if (tid < off) sb[tid] = fmaxf(sb[tid], sb[tid + off]);
    __syncthreads();
  }
  ym = sb[0]; __syncthreads();

  float gm = -3.0e38f;
  for (int h = tid; h < Hh; h += 256) gm = fmaxf(gm, gamma[h]);
  sb[tid] = gm; __syncthreads();
  for (int off = 128; off; off >>= 1) {
    if (tid < off) sb[tid] = fmaxf(sb[tid], sb[tid + off]);
    __syncthreads();
  }
  gm = sb[0]; __syncthreads();

  float s1 = 0.f, s2 = 0.f;
  for (int h = tid; h < Hh; h += 256) {
    float gv = gamma[h] - gm;
    s1 += __expf(gv);
    s2 += __expf(gv + Y255[(size_t)b * Hh + h] - ym);
  }
  sb[tid] = s1; __syncthreads();
  for (int off = 128; off; off >>= 1) {
    if (tid < off) sb[tid] += sb[tid + off];
    __syncthreads();
  }
  s1 = sb[0]; __syncthreads();
  sb[tid] = s2; __syncthreads();
  for (int off = 128; off; off >>= 1) {
    if (tid < off) sb[tid] += sb[tid + off];
    __syncthreads();
  }
  s2 = sb[0];

  if (tid == 0)
    out[(size_t)Ss * Hh * Bb + b] = __logf(s2) - __logf(s1) + ym;
}

// ---------------------------------------------------------------------------
extern "C" void kernel_launch(void* const* d_in, const int* in_sizes, int n_in,
                              void* d_out, int out_size, void* d_ws, size_t ws_size,
                              hipStream_t stream) {
  (void)in_sizes; (void)n_in; (void)out_size;
  const int*   ids   = (const int*)d_in[0];
  const float* alpha = (const float*)d_in[1];
  const float* beta  = (const float*)d_in[2];
  const float* gamma = (const float*)d_in[3];
  float* out = (float*)d_out;
  char* ws = (char*)d_ws;

  if (ws_size < WS_NEED) return;   // clean fail rather than OOB

  ushort_t* Zbuf = (ushort_t*)(ws + Z_OFF);
  float*    Y255 = (float*)(ws + Y_OFF);

  // Epoch-pattern init: phys0/phys1 -> sign=1 (0x8080), phys2 -> sign=0.
  // Each slot's first poll expects the opposite parity, so consumers block
  // until real data lands; also scrubs the previous launch's leftovers.
  hipMemsetAsync(ws + Z_OFF, 0x80, 2 * Z_SLOT, stream);
  hipMemsetAsync(ws + Z_OFF + 2 * Z_SLOT, 0x00, Z_SLOT, stream);

  {
    const float* a_alpha = alpha;
    const float* a_beta  = beta;
    const int*   a_ids   = ids;
    ushort_t* a_z = Zbuf;  float* a_y = Y255;  float* a_out = out;
    void* args[] = {(void*)&a_alpha, (void*)&a_beta, (void*)&a_ids,
                    (void*)&a_z, (void*)&a_y, (void*)&a_out};
    hipError_t e = hipLaunchCooperativeKernel((const void*)hmm_persist,
                                              dim3(256), dim3(256), args, 0, stream);
    if (e != hipSuccess) {
      hipLaunchKernelGGL(hmm_persist, dim3(256), dim3(256), 0, stream,
                         alpha, beta, ids, Zbuf, Y255, out);
    }
  }

  hipLaunchKernelGGL(final_k, dim3(Bb), dim3(256), 0, stream, gamma, Y255, out);
}